// Round 1
// 201.551 us; speedup vs baseline: 1.0790x; 1.0790x over previous
//
#include <hip/hip_runtime.h>

#define EDGES 4096
#define NNODES 256
// x: (256, 784), W: (256, 784, 128), b: (256, 128), edge_index: (2, 4096), ew: (4096)
// out: (256, 128)

typedef unsigned short u16;
typedef float f32x4 __attribute__((ext_vector_type(4)));

// ---------------------------------------------------------------------------
// K1: compute c[n] = (1/N) * r[n], where r^T = 1^T * Prod_{e=E-1..0}(I + w_e E_{t,s})
// Reverse scan: for e = E-1..0: r[s_e] += w_e * r[t_e].
// Exact via triangular system: rho_e = 1 + sum_{e'>e, s_{e'}=t_e} w_{e'} rho_{e'},
// r[n] = 1 + sum_{e: s_e=n} w_e rho_e.  Neumann iteration (nilpotent L, ||L||~0.03)
// with 5 passes -> error ~1e-8.
// v2: 1024 threads (4x parallelism on edge-phases); single-wave shfl scan
//     (1 barrier instead of 16).
// ---------------------------------------------------------------------------
__global__ __launch_bounds__(1024) void k1_coeff(const int* __restrict__ ei,
                                                 const float* __restrict__ ew,
                                                 float* __restrict__ c_out) {
    __shared__ __align__(16) char smem[59648];
    float* w_q    = (float*)(smem);              // [0, 16K)      per-position weight
    u16*   s_e    = (u16*)  (smem + 16384);      // [16K, 24K)    phase A
    u16*   t_e    = (u16*)  (smem + 24576);      // [24K, 32K)    phase A..gather
    float* rho    = (float*)(smem + 16384);      // [16K, 32K)    after gather
    u16*   id_q   = (u16*)  (smem + 32768);      // [32K, 40K)    sorted ids
    u16*   t_q    = (u16*)  (smem + 40960);      // [40K, 48K)    target per position
    float* sfx    = (float*)(smem + 32768);      // [32K, 48K)    after search
    u16*   id_u   = (u16*)  (smem + 49152);      // [48K, 56K)    unsorted fill
    u16*   start_q= (u16*)  (smem + 49152);      // aliases id_u (dead by then)
    int*   offs   = (int*)  (smem + 57344);      // 257 ints
    int*   fillc  = (int*)  (smem + 58372);      // 256 ints

    const int tid = threadIdx.x;

    // P0: load edges, init counters
    for (int j = tid; j < EDGES; j += 1024) {
        s_e[j] = (u16)ei[j];
        t_e[j] = (u16)ei[EDGES + j];
    }
    if (tid < 256) fillc[tid] = 0;
    __syncthreads();

    // P1: count by source
    for (int j = tid; j < EDGES; j += 1024) atomicAdd(&fillc[s_e[j]], 1);
    __syncthreads();

    // P2: exclusive scan -> offs[0..256], single wave, no internal barriers.
    // Lane l owns fillc[4l..4l+3]; wave-inclusive shfl_up scan of the 4-sums.
    if (tid < 64) {
        const int base = tid << 2;
        int c0 = fillc[base + 0], c1 = fillc[base + 1];
        int c2 = fillc[base + 2], c3 = fillc[base + 3];
        int s = c0 + c1 + c2 + c3;
        int run = s;
        #pragma unroll
        for (int d = 1; d < 64; d <<= 1) {
            int o = __shfl_up(run, d, 64);
            if (tid >= d) run += o;
        }
        const int excl = run - s;                // exclusive prefix of this 4-group
        offs[base + 0] = excl;
        offs[base + 1] = excl + c0;
        offs[base + 2] = excl + c0 + c1;
        offs[base + 3] = excl + c0 + c1 + c2;
        if (tid == 63) offs[256] = run;          // == EDGES
    }
    __syncthreads();

    // P3: fill counters = offs
    if (tid < 256) fillc[tid] = offs[tid];
    __syncthreads();

    // P4: unsorted fill
    for (int j = tid; j < EDGES; j += 1024) {
        int pos = atomicAdd(&fillc[s_e[j]], 1);
        id_u[pos] = (u16)j;
    }
    __syncthreads();

    // P5: rank within bucket -> sorted scatter (ids unique, so rank is exact)
    for (int j = tid; j < EDGES; j += 1024) {
        int s = s_e[j];
        int lo = offs[s], hi = offs[s + 1];
        int rank = 0;
        for (int q = lo; q < hi; ++q) rank += (id_u[q] < j) ? 1 : 0;
        id_q[lo + rank] = (u16)j;
    }
    __syncthreads();

    // P6: gather weight and target into position order
    for (int q = tid; q < EDGES; q += 1024) {
        int e = id_q[q];
        w_q[q] = ew[e];
        t_q[q] = t_e[e];
    }
    __syncthreads();

    // P7: binary search: first position in bucket(t) with id > my id
    for (int q = tid; q < EDGES; q += 1024) {
        int myid = id_q[q];
        int t = t_q[q];
        int lo = offs[t], hi = offs[t + 1];
        const int hi0 = hi;
        while (lo < hi) {
            int mid = (lo + hi) >> 1;
            if (id_q[mid] > myid) hi = mid; else lo = mid + 1;
        }
        start_q[q] = (lo < hi0) ? (u16)lo : (u16)0xFFFFu;
    }
    __syncthreads();

    // P8: rho init
    for (int q = tid; q < EDGES; q += 1024) rho[q] = 1.0f;
    __syncthreads();

    // P9: Neumann passes: rho <- 1 + suffix_{bucket(t)}(w * rho)[start]
    for (int pass = 0; pass < 5; ++pass) {
        for (int q = tid; q < EDGES; q += 1024) sfx[q] = w_q[q] * rho[q];
        __syncthreads();
        if (tid < 256) {   // per-bucket suffix sum in place (thread tid owns bucket tid)
            int lo = offs[tid], hi = offs[tid + 1];
            float run = 0.0f;
            for (int q = hi - 1; q >= lo; --q) { run += sfx[q]; sfx[q] = run; }
        }
        __syncthreads();
        for (int q = tid; q < EDGES; q += 1024) {
            int st = start_q[q];
            rho[q] = 1.0f + ((st != 0xFFFF) ? sfx[st] : 0.0f);
        }
        __syncthreads();
    }

    // P10: finalize r[n] = 1 + sum_{bucket n} w*rho ; c = r/256
    if (tid < 256) {
        int lo = offs[tid], hi = offs[tid + 1];
        float acc = 0.0f;
        for (int q = lo; q < hi; ++q) acc += w_q[q] * rho[q];
        c_out[tid] = (1.0f + acc) * (1.0f / 256.0f);
    }
}

// ---------------------------------------------------------------------------
// K2: Wc[i,h] = sum_n c[n] * W[n,i,h]  (rows 0..783), Wc[784,h] = sum_n c[n]*b[n,h]
// v2: 16-way split over n (1584 blocks: tail waste 10% -> 3%), nontemporal
// loads on the read-once W stream, fp32 atomic accumulation. Reads W once.
// ---------------------------------------------------------------------------
__global__ __launch_bounds__(256) void k2_wc(const float* __restrict__ W,
                                             const float* __restrict__ bvec,
                                             const float* __restrict__ c,
                                             float* __restrict__ Wc) {
    const int bx = blockIdx.x;   // 0..98 (98 = bias row)
    const int p  = blockIdx.y;   // 0..15
    const int n0 = p * 16;

    if (bx == 98) {
        int tid = threadIdx.x;
        if (tid < 32) {
            const f32x4* b4 = (const f32x4*)bvec;
            f32x4 acc = {0.f, 0.f, 0.f, 0.f};
            #pragma unroll
            for (int n = 0; n < 16; ++n) {
                float cn = c[n0 + n];
                f32x4 v = b4[(n0 + n) * 32 + tid];
                acc += v * cn;
            }
            float* dst = Wc + 784 * 128 + tid * 4;
            atomicAdd(dst + 0, acc.x);
            atomicAdd(dst + 1, acc.y);
            atomicAdd(dst + 2, acc.z);
            atomicAdd(dst + 3, acc.w);
        }
        return;
    }

    const int j  = bx * 256 + threadIdx.x;   // < 25088
    const int i  = j >> 5;                   // 0..783
    const int h4 = j & 31;                   // 0..31
    const f32x4* W4 = (const f32x4*)W;       // index: (n*784 + i)*32 + h4
    f32x4 acc = {0.f, 0.f, 0.f, 0.f};
    #pragma unroll
    for (int n = 0; n < 16; ++n) {
        float cn = c[n0 + n];
        f32x4 v = __builtin_nontemporal_load(&W4[((size_t)(n0 + n) * 784 + i) * 32 + h4]);
        acc += v * cn;
    }
    float* dst = Wc + i * 128 + h4 * 4;
    atomicAdd(dst + 0, acc.x);
    atomicAdd(dst + 1, acc.y);
    atomicAdd(dst + 2, acc.z);
    atomicAdd(dst + 3, acc.w);
}

// ---------------------------------------------------------------------------
// K3: out[b,h] = sum_i x[b,i]*Wc[i,h] + Wc[784,h]
// grid (16 b-groups of 16 rows) x (16 k-chunks of 49), atomic accumulate.
// ---------------------------------------------------------------------------
__global__ __launch_bounds__(256) void k3_gemm(const float* __restrict__ x,
                                               const float* __restrict__ Wc,
                                               float* __restrict__ out) {
    const int bg = blockIdx.x;   // 0..15
    const int kc = blockIdx.y;   // 0..15
    const int i0 = kc * 49;
    __shared__ float xs[16][49];
    const int tid = threadIdx.x;

    for (int idx = tid; idx < 16 * 49; idx += 256) {
        int row = idx / 49, ii = idx - row * 49;
        xs[row][ii] = x[(bg * 16 + row) * 784 + i0 + ii];
    }
    __syncthreads();

    const int h  = tid & 127;
    const int bh = tid >> 7;     // 0..1
    float acc[8];
    #pragma unroll
    for (int j = 0; j < 8; ++j) acc[j] = 0.0f;

    #pragma unroll 7
    for (int ii = 0; ii < 49; ++ii) {
        float wv = Wc[(i0 + ii) * 128 + h];
        #pragma unroll
        for (int j = 0; j < 8; ++j) acc[j] += xs[bh * 8 + j][ii] * wv;
    }

    if (kc == 15) {   // bias row contributes exactly once
        float bch = Wc[784 * 128 + h];
        #pragma unroll
        for (int j = 0; j < 8; ++j) acc[j] += bch;
    }

    #pragma unroll
    for (int j = 0; j < 8; ++j)
        atomicAdd(&out[(bg * 16 + bh * 8 + j) * 128 + h], acc[j]);
}

extern "C" void kernel_launch(void* const* d_in, const int* in_sizes, int n_in,
                              void* d_out, int out_size, void* d_ws, size_t ws_size,
                              hipStream_t stream) {
    const float* x  = (const float*)d_in[0];
    const float* W  = (const float*)d_in[1];
    const float* bv = (const float*)d_in[2];
    const int*   ei = (const int*)d_in[3];
    const float* ew = (const float*)d_in[4];
    float* out = (float*)d_out;

    float* c_ws = (float*)d_ws;                  // 256 floats
    float* Wc   = (float*)d_ws + 256;            // 785*128 floats (row 784 = bias)

    hipMemsetAsync(out, 0, (size_t)256 * 128 * sizeof(float), stream);
    hipMemsetAsync(Wc, 0, (size_t)785 * 128 * sizeof(float), stream);

    k1_coeff<<<1, 1024, 0, stream>>>(ei, ew, c_ws);
    k2_wc<<<dim3(99, 16), 256, 0, stream>>>(W, bv, c_ws, Wc);
    k3_gemm<<<dim3(16, 16), 256, 0, stream>>>(x, Wc, out);
}